// Round 1
// 102.764 us; speedup vs baseline: 1.0577x; 1.0577x over previous
//
#include <hip/hip_runtime.h>
#include <hip/hip_bf16.h>
#include <hip/hip_fp16.h>
#include <math.h>

#define BB   8
#define DD   1024

typedef short bh8 __attribute__((ext_vector_type(8)));
typedef float f32x4 __attribute__((ext_vector_type(4)));
typedef _Float16 h2f __attribute__((ext_vector_type(2)));

__device__ __forceinline__ ushort f2bf(float f) {
    uint u = __builtin_bit_cast(uint, f);
    u += 0x7fffu + ((u >> 16) & 1u);
    return (ushort)(u >> 16);
}
__device__ __forceinline__ float asf(uint u)  { return __builtin_bit_cast(float, u); }
__device__ __forceinline__ uint  pkh(float a, float b) {
    return __builtin_bit_cast(uint, __builtin_amdgcn_cvt_pkrtz(a, b));
}
__device__ __forceinline__ h2f ash2f(uint u) { return __builtin_bit_cast(h2f, u); }

// v_dot2_f32_f16: a.x*b.x + a.y*b.y + c, f32 accumulate (1 VALU op).
#if __has_builtin(__builtin_amdgcn_fdot2)
__device__ __forceinline__ float fdot2h(h2f a, h2f b, float c) {
    return __builtin_amdgcn_fdot2(a, b, c, false);
}
#else
__device__ __forceinline__ float fdot2h(h2f a, h2f b, float c) {
    return fmaf((float)a.x, (float)b.x, fmaf((float)a.y, (float)b.y, c));
}
#endif

// hardware packed f32->bf16 RTNE (no builtin on gfx950; asm per guide recipe)
__device__ __forceinline__ uint cvtpk_bf16(float a, float b) {
    uint r;
    asm("v_cvt_pk_bf16_f32 %0, %1, %2" : "=v"(r) : "v"(a), "v"(b));
    return r;
}
__device__ __forceinline__ ushort cvt1_bf16(float a) {
    uint r;
    asm("v_cvt_pk_bf16_f32 %0, %1, %2" : "=v"(r) : "v"(a), "v"(a));
    return (ushort)r;
}

// overflow-safe tanh-form gelu: x * sigmoid(1.5957691x + 0.1427096x^3)
// exp folded to exp2 (constants pre-multiplied by log2e); rcp instead of
// precise-div (saves ~8 VALU/call).
__device__ __forceinline__ float gelu_fast(float x) {
    float x2 = x * x;
#if __has_builtin(__builtin_amdgcn_exp2f)
    float e = __builtin_amdgcn_exp2f(x * fmaf(x2, -0.20588652f, -2.3022082f));
#else
    float e = __expf(-(1.5957691216f * x + 0.14270963f * x * x2));
#endif
    return x * __builtin_amdgcn_rcpf(1.0f + e);
}
__device__ __forceinline__ float sig63(float v) {
    return 63.0f * __builtin_amdgcn_rcpf(1.0f + __expf(-v));
}

// ---------------------------------------------------------------------------
// kT: weight prep (unchanged; bf16 fragment packs for MFMA).
// ---------------------------------------------------------------------------
__global__ __launch_bounds__(256) void kT_pack(
    const float* __restrict__ w_idx, const float* __restrict__ w_mask,
    const float* __restrict__ w_proj, const float* __restrict__ w1,
    const float* __restrict__ w2,
    float* __restrict__ w_catT,
    ushort* __restrict__ w_projP, ushort* __restrict__ w1P,
    ushort* __restrict__ w2P)
{
    int e = blockIdx.x * 256 + threadIdx.x;
    if (e < 49152) {                    // w_catT[k*192 + o] = W[o][k]
        int k = e / 192, o = e - k * 192;
        const float* src = (o < 64) ? (w_idx + (size_t)o * 256)
                                    : (w_mask + (size_t)(o - 64) * 256);
        w_catT[e] = src[k];
    } else if (e < 50176) {             // w_proj (128,64): B[k=c][n=dch]
        int g = e - 49152; int nt = g >> 7, ks = (g >> 6) & 1, l = g & 63;
        int n = nt * 16 + (l & 15), k0 = ks * 32 + (l >> 4) * 8;
        ushort* dst = w_projP + (size_t)g * 8;
        #pragma unroll
        for (int j = 0; j < 8; ++j) dst[j] = f2bf(w_proj[n * 64 + k0 + j]);
    } else if (e < 58368) {             // w_mlp1 (512,128): B[k][n]
        int g = e - 50176; int nt = g >> 8, ks = (g >> 6) & 3, l = g & 63;
        int n = nt * 16 + (l & 15), k0 = ks * 32 + (l >> 4) * 8;
        ushort* dst = w1P + (size_t)g * 8;
        #pragma unroll
        for (int j = 0; j < 8; ++j) dst[j] = f2bf(w1[n * 128 + k0 + j]);
    } else if (e < 66560) {             // w_mlp2 (128,512): B[k][n]
        int g = e - 58368; int nt = g >> 10, ks = (g >> 6) & 15, l = g & 63;
        int n = nt * 16 + (l & 15), k0 = ks * 32 + (l >> 4) * 8;
        ushort* dst = w2P + (size_t)g * 8;
        #pragma unroll
        for (int j = 0; j < 8; ++j) dst[j] = f2bf(w2[n * 512 + k0 + j]);
    }
}

// ---------------------------------------------------------------------------
// k0: coords+mask GEMM (f32 VALU, 8 rows/block) + meta epilogue.
// Meta per (tile,row m), 4 corners x 8 words:
//  [0]=T1 byte off (pt*1024) [1]=T2 byte off (pt*128)
//  [2]=f16(m0,m1) [3]=f16(m2,m3) [4]=f16(m4,m5) [5]=f16(m6,m7) [6]=m8 f32 [7]=0
//  m = s * {1, dy, dy^2, dx, dx^2, dx*dy, dx*dy^2, dx^2*dy, dx^2*dy^2}
// ---------------------------------------------------------------------------
__global__ __launch_bounds__(256) void k0_coords_mask(
    const float* __restrict__ x, const float* __restrict__ w_catT,
    const float* __restrict__ b_idx, const float* __restrict__ b_mask,
    float* __restrict__ maskw, uint* __restrict__ meta)
{
    __shared__ float xs[8][256];
    __shared__ float sOut[8][192];
    int t = threadIdx.x;
    size_t rowbase = (size_t)blockIdx.x * 8;

    for (int i = t; i < 2048; i += 256) xs[i >> 8][i & 255] = x[rowbase * 256 + i];
    __syncthreads();

    if (t < 192) {
        float acc[8] = {0.f, 0.f, 0.f, 0.f, 0.f, 0.f, 0.f, 0.f};
        #pragma unroll 4
        for (int k = 0; k < 256; ++k) {
            float wv = w_catT[k * 192 + t];
            #pragma unroll
            for (int r = 0; r < 8; ++r) acc[r] += xs[r][k] * wv;
        }
        #pragma unroll
        for (int r = 0; r < 8; ++r) sOut[r][t] = acc[r];
    }
    __syncthreads();

    if (t < 128) {
        int row = t >> 4, u = t & 15, br = u >> 3, nr = u & 7;
        int c0 = br * 32 + nr * 4;
        float x1 = sig63(sOut[row][c0 + 0] + b_idx[c0 + 0]);
        float y1 = sig63(sOut[row][c0 + 1] + b_idx[c0 + 1]);
        float x2 = sig63(sOut[row][c0 + 2] + b_idx[c0 + 2]);
        float y2 = sig63(sOut[row][c0 + 3] + b_idx[c0 + 3]);
        int X1 = (int)ceilf(x1); X1 = X1 < 1 ? 1 : (X1 > 63 ? 63 : X1);
        int X2 = (int)ceilf(x2); X2 = X2 < 1 ? 1 : (X2 > 63 ? 63 : X2);
        int Y1 = (int)ceilf(y1); Y1 = Y1 < 1 ? 1 : (Y1 > 63 ? 63 : Y1);
        int Y2 = (int)ceilf(y2); Y2 = Y2 < 1 ? 1 : (Y2 > 63 ? 63 : Y2);
        float dxa = (float)X1 - x1, dxb = (float)X2 - x2;
        float dya = (float)Y1 - y1, dyb = (float)Y2 - y2;
        int   Xc[4] = {X2, X1, X2, X1};
        int   Yc[4] = {Y2, Y2, Y1, Y1};
        float sg[4] = {1.f, -1.f, -1.f, 1.f};
        float dxc[4] = {dxb, dxa, dxb, dxa};
        float dyc[4] = {dyb, dyb, dya, dya};
        uint* mr = meta + (((rowbase + row) * 16) + (size_t)u) * 32;
        #pragma unroll
        for (int c = 0; c < 4; ++c) {
            uint pt = (uint)(Xc[c] * 64 + Yc[c]);
            float s = sg[c], dx = dxc[c], dy = dyc[c];
            float dx2 = dx * dx, dy2 = dy * dy;
            uint4 wa, wb;
            wa.x = pt * 1024u;
            wa.y = pt * 128u;
            wa.z = pkh(s, s * dy);
            wa.w = pkh(s * dy2, s * dx);
            wb.x = pkh(s * dx2, s * dx * dy);
            wb.y = pkh(s * dx * dy2, s * dx2 * dy);
            wb.z = __builtin_bit_cast(uint, s * dx2 * dy2);
            wb.w = 0u;
            *(uint4*)(mr + c * 8 + 0) = wa;
            *(uint4*)(mr + c * 8 + 4) = wb;
        }
    } else {
        int tt = t - 128;
        int row = tt >> 4, br = (tt >> 3) & 1, g = tt & 7;
        float lg[8];
        float mx = -1e30f;
        #pragma unroll
        for (int nr = 0; nr < 8; ++nr) {
            int idx = br * 64 + nr * 8 + g;
            lg[nr] = sOut[row][64 + idx] + b_mask[idx];
            mx = fmaxf(mx, lg[nr]);
        }
        float s = 0.f;
        #pragma unroll
        for (int nr = 0; nr < 8; ++nr) { lg[nr] = __expf(lg[nr] - mx); s += lg[nr]; }
        float inv = __builtin_amdgcn_rcpf(s);
        #pragma unroll
        for (int nr = 0; nr < 8; ++nr)
            maskw[(rowbase + row) * 128 + br * 64 + nr * 8 + g] = lg[nr] * inv;
    }
}

// ---------------------------------------------------------------------------
// k1: 9-coefficient texture per (b,X,Y,c), channel-last **f16**.
// T1[pt*64+c] = uint4 {f16(c0,c1), f16(c2,c3), f16(c4,c5), f16(c6,c7)};
// T2[pt*64+c] = f16(c8).  16 channels/block for occupancy.
// ---------------------------------------------------------------------------
__global__ __launch_bounds__(256) void k1_coeff(
    const float* __restrict__ I, const float* __restrict__ IX,
    const float* __restrict__ IY, const float* __restrict__ IT,
    uint4* __restrict__ T1, ushort* __restrict__ T2)
{
    __shared__ float tI[16][65], tIp[16][65], tX[16][65];
    __shared__ float tY[16][65], tYp[16][65], tT[16][65];
    int bid = blockIdx.x;                 // b(8) x h(64) x chunk(4)
    int chunk = bid & 3, h = (bid >> 2) & 63, b = bid >> 8;
    int hp = h > 0 ? h - 1 : 0;
    int cb = chunk * 16;
    int t = threadIdx.x;
    size_t inb  = (size_t)b * 262144 + (size_t)h  * 64;
    size_t inbp = (size_t)b * 262144 + (size_t)hp * 64;

    #pragma unroll
    for (int i = 0; i < 4; ++i) {
        int idx = i * 256 + t; int c = idx >> 6, w = idx & 63;
        size_t o = (size_t)(cb + c) * 4096 + w;
        tI[c][w]  = I[inb + o];
        tIp[c][w] = I[inbp + o];
        tX[c][w]  = IX[inb + o];
        tY[c][w]  = IY[inb + o];
        tYp[c][w] = IY[inbp + o];
        tT[c][w]  = IT[inb + o];
    }
    __syncthreads();

    #pragma unroll
    for (int i = 0; i < 4; ++i) {
        int idx = i * 256 + t; int w = idx >> 4, c = idx & 15;
        int wm = w > 0 ? w - 1 : 0;
        float I00 = tI[c][w], I0m = tI[c][wm];
        float Im0 = tIp[c][w], Imm = tIp[c][wm];
        float E1  = tX[c][w]  - 0.5f * I00;
        float E1m = tX[c][wm] - 0.5f * I0m;
        float E2  = tY[c][w]  - 0.5f * I00;
        float E2m = tYp[c][w] - 0.5f * Im0;
        float v0 = tT[c][w];
        float v1 = -E1;
        float v2 = 0.5f * (E1 - E1m);
        float v3 = -E2;
        float v4 = 0.5f * (E2 - E2m);
        float v5 = I00;
        float v6 = 0.5f * (I0m - I00);
        float v7 = 0.5f * (Im0 - I00);
        float v8 = 0.25f * ((Imm - I0m) - (Im0 - I00));
        size_t pt = (((size_t)b * 4096) + (size_t)h * 64 + w) * 64 + (cb + c);
        uint4 o4;
        o4.x = pkh(v0, v1);
        o4.y = pkh(v2, v3);
        o4.z = pkh(v4, v5);
        o4.w = pkh(v6, v7);
        T1[pt] = o4;
        T2[pt] = (ushort)(pkh(v8, 0.f) & 0xffffu);
    }
}

// ---------------------------------------------------------------------------
// k2: fused sampling + rects GEMM + gelu + mask-sum + LN1.
// Per corner: 2 loads + 4x v_dot2_f32_f16 (f32 accumulate) + e8 fma.
// Corner accumulation entirely in f32 (box-difference cancellation kept in
// f32; fdot2 is MORE precise than the previous f16 hfma2 chain).
// ---------------------------------------------------------------------------
__global__ __launch_bounds__(256) void k2_rects(
    const uint4* __restrict__ T1, const ushort* __restrict__ T2,
    const uint* __restrict__ meta,
    const ushort* __restrict__ w_projP, const float* __restrict__ b_proj,
    const float* __restrict__ maskw, const float* __restrict__ g1,
    const float* __restrict__ beta1, float* __restrict__ mid)
{
    __shared__ __align__(16) uint meta_lds[16][32];
    __shared__ __align__(16) float S_lds[16][68];
    __shared__ float mrow[128];
    __shared__ float outr[2][128];
    int bid = blockIdx.x;
    int b = bid & 7, d = bid >> 3;
    int t = threadIdx.x, w = t >> 6, l = t & 63;
    size_t tile = (size_t)b * DD + d;
    if (t < 128) {
        uint4 mv = *(const uint4*)(meta + tile * 512 + (size_t)t * 4);
        *(uint4*)(&meta_lds[0][0] + t * 4) = mv;
    }
    if (t >= 128) mrow[t - 128] = maskw[tile * 128 + (t - 128)];

    bh8 bf[2][2];
    #pragma unroll
    for (int ni = 0; ni < 2; ++ni) {
        int nt = w * 2 + ni;
        #pragma unroll
        for (int ks = 0; ks < 2; ++ks)
            bf[ni][ks] = *(const bh8*)(w_projP + ((size_t)(nt * 2 + ks) * 64 + l) * 8);
    }
    __syncthreads();
    const char* t1b = ((const char*)T1) + ((size_t)b << 22) + (size_t)(l * 16);
    const char* t2b = ((const char*)T2) + ((size_t)b << 19) + (size_t)(l * 2);

    #pragma unroll
    for (int rr = 0; rr < 4; ++rr) {
        int m = w * 4 + rr;              // row = br*8 + nr
        uint4 wa[4], wb[4];
        #pragma unroll
        for (int c = 0; c < 4; ++c) {
            wa[c] = *(const uint4*)&meta_lds[m][c * 8 + 0];
            wb[c] = *(const uint4*)&meta_lds[m][c * 8 + 4];
        }
        uint4 q[4]; ushort e8[4];
        #pragma unroll
        for (int c = 0; c < 4; ++c) {
            q[c]  = *(const uint4*)(t1b + wa[c].x);
            e8[c] = *(const ushort*)(t2b + wa[c].y);
        }
        float acc0 = 0.f, acc1 = 0.f;
        #pragma unroll
        for (int c = 0; c < 4; ++c) {
            float ev = __half2float(__builtin_bit_cast(__half, e8[c]));
            float cv = fmaf(asf(wb[c].z), ev, 0.f);
            cv = fdot2h(ash2f(wb[c].y), ash2f(q[c].w), cv);
            cv = fdot2h(ash2f(wb[c].x), ash2f(q[c].z), cv);
            cv = fdot2h(ash2f(wa[c].w), ash2f(q[c].y), cv);
            cv = fdot2h(ash2f(wa[c].z), ash2f(q[c].x), cv);
            if (c & 1) acc1 += cv; else acc0 += cv;
        }
        S_lds[m][l] = acc0 + acc1;
    }
    __syncthreads();

    // MFMA: A from S_lds (bf16 via v_cvt_pk_bf16_f32), B = w_proj fragments
    int am = l & 15, q = l >> 4;
    bh8 a0, a1;
    {
        float4 va = *(const float4*)&S_lds[am][q * 8];
        float4 vb = *(const float4*)&S_lds[am][q * 8 + 4];
        uint4 ua;
        ua.x = cvtpk_bf16(va.x, va.y);
        ua.y = cvtpk_bf16(va.z, va.w);
        ua.z = cvtpk_bf16(vb.x, vb.y);
        ua.w = cvtpk_bf16(vb.z, vb.w);
        a0 = __builtin_bit_cast(bh8, ua);
        float4 vc = *(const float4*)&S_lds[am][32 + q * 8];
        float4 vd = *(const float4*)&S_lds[am][32 + q * 8 + 4];
        uint4 ub;
        ub.x = cvtpk_bf16(vc.x, vc.y);
        ub.y = cvtpk_bf16(vc.z, vc.w);
        ub.z = cvtpk_bf16(vd.x, vd.y);
        ub.w = cvtpk_bf16(vd.z, vd.w);
        a1 = __builtin_bit_cast(bh8, ub);
    }
    f32x4 cc[2];
    cc[0] = (f32x4){0.f, 0.f, 0.f, 0.f};
    cc[1] = (f32x4){0.f, 0.f, 0.f, 0.f};
    cc[0] = __builtin_amdgcn_mfma_f32_16x16x32_bf16(a0, bf[0][0], cc[0], 0, 0, 0);
    cc[0] = __builtin_amdgcn_mfma_f32_16x16x32_bf16(a1, bf[0][1], cc[0], 0, 0, 0);
    cc[1] = __builtin_amdgcn_mfma_f32_16x16x32_bf16(a0, bf[1][0], cc[1], 0, 0, 0);
    cc[1] = __builtin_amdgcn_mfma_f32_16x16x32_bf16(a1, bf[1][1], cc[1], 0, 0, 0);

    int cl = l & 15;
    #pragma unroll
    for (int ni = 0; ni < 2; ++ni) {
        int nt = w * 2 + ni;
        int col = nt * 16 + cl;
        float bpv = b_proj[col];
        float p = 0.f;
        #pragma unroll
        for (int reg = 0; reg < 4; ++reg) {
            int r = q * 4 + reg;                       // row = br*8+nr
            float v = cc[ni][reg] + bpv;
            p += gelu_fast(v) * mrow[(r >> 3) * 64 + (r & 7) * 8 + nt];
        }
        p += __shfl_xor(p, 16, 64);
        if (q == 0) outr[0][col] = p;
        else if (q == 2) outr[1][col] = p;
    }
    __syncthreads();

    if (w < 2) {
        float v0 = outr[w][l], v1 = outr[w][l + 64];
        float s = v0 + v1, sq = v0 * v0 + v1 * v1;
        #pragma unroll
        for (int mm = 32; mm > 0; mm >>= 1) {
            s  += __shfl_xor(s, mm, 64);
            sq += __shfl_xor(sq, mm, 64);
        }
        float mu  = s * (1.0f / 128.0f);
        float var = sq * (1.0f / 128.0f) - mu * mu;
        float rs  = rsqrtf(var + 1e-5f);
        size_t ob = (tile * 2 + w) * 128;
        mid[ob + l]      = (v0 - mu) * rs * g1[l]      + beta1[l];
        mid[ob + l + 64] = (v1 - mu) * rs * g1[l + 64] + beta1[l + 64];
    }
}

// ---------------------------------------------------------------------------
// k4: MLP 128->512(gelu)->128 via MFMA, 16 rows/block, + LN2 + residual.
// bf16 converts via v_cvt_pk_bf16_f32; gelu via exp2+rcp.
// ---------------------------------------------------------------------------
__global__ __launch_bounds__(256) void k4_mlp(
    const float* __restrict__ mid, const ushort* __restrict__ w1P,
    const float* __restrict__ b1, const ushort* __restrict__ w2P,
    const float* __restrict__ b2, const float* __restrict__ g2,
    const float* __restrict__ beta2, float* __restrict__ outp)
{
    __shared__ float xr[16][132];
    __shared__ __align__(16) ushort Af[4][64][8];
    __shared__ __align__(16) ushort H[16][520];
    __shared__ float oo[16][128];
    __shared__ float b1s[512];
    __shared__ float b2s[128], g2s[128], bt2s[128];
    int t = threadIdx.x, w = t >> 6, l = t & 63;
    int bid = blockIdx.x;
    int mt = (bid & 7) * 128 + (bid >> 3);   // XCD-local by batch
    size_t rowbase = (size_t)mt * 16;

    for (int i = t; i < 2048; i += 256) xr[i >> 7][i & 127] = mid[rowbase * 128 + i];
    for (int i = t; i < 512; i += 256) b1s[i] = b1[i];
    if (t < 128) { b2s[t] = b2[t]; g2s[t] = g2[t]; bt2s[t] = beta2[t]; }
    __syncthreads();

    {
        int ks = t >> 6, m = l & 15, c0 = ks * 32 + (l >> 4) * 8;
        uint* dst = (uint*)&Af[ks][l][0];
        #pragma unroll
        for (int j = 0; j < 4; ++j)
            dst[j] = cvtpk_bf16(xr[m][c0 + 2 * j], xr[m][c0 + 2 * j + 1]);
    }
    __syncthreads();

    f32x4 c1[8];
    #pragma unroll
    for (int i = 0; i < 8; ++i) c1[i] = (f32x4){0.f, 0.f, 0.f, 0.f};
    bh8 a[4];
    #pragma unroll
    for (int ks = 0; ks < 4; ++ks) a[ks] = *(const bh8*)&Af[ks][l][0];
    #pragma unroll
    for (int ni = 0; ni < 8; ++ni) {
        int nt = w * 8 + ni;
        #pragma unroll
        for (int ks = 0; ks < 4; ++ks) {
            bh8 bfr = *(const bh8*)(w1P + ((size_t)(nt * 4 + ks) * 64 + l) * 8);
            c1[ni] = __builtin_amdgcn_mfma_f32_16x16x32_bf16(a[ks], bfr, c1[ni], 0, 0, 0);
        }
    }
    #pragma unroll
    for (int ni = 0; ni < 8; ++ni) {
        int nt = w * 8 + ni;
        int col = nt * 16 + (l & 15);
        int r0 = (l >> 4) * 4;
        #pragma unroll
        for (int reg = 0; reg < 4; ++reg)
            H[r0 + reg][col] = cvt1_bf16(gelu_fast(c1[ni][reg] + b1s[col]));
    }
    __syncthreads();

    f32x4 c2[2];
    c2[0] = (f32x4){0.f, 0.f, 0.f, 0.f};
    c2[1] = (f32x4){0.f, 0.f, 0.f, 0.f};
    const char* hb = (const char*)&H[0][0];
    #pragma unroll
    for (int ks2 = 0; ks2 < 16; ++ks2) {
        bh8 af = *(const bh8*)(hb + (l & 15) * 1040 + ks2 * 64 + (l >> 4) * 16);
        #pragma unroll
        for (int i = 0; i < 2; ++i) {
            int nt2 = w * 2 + i;
            bh8 bfr = *(const bh8*)(w2P + ((size_t)(nt2 * 16 + ks2) * 64 + l) * 8);
            c2[i] = __builtin_amdgcn_mfma_f32_16x16x32_bf16(af, bfr, c2[i], 0, 0, 0);
        }
    }
    #pragma unroll
    for (int i = 0; i < 2; ++i) {
        int col = (w * 2 + i) * 16 + (l & 15);
        int r0 = (l >> 4) * 4;
        #pragma unroll
        for (int reg = 0; reg < 4; ++reg) oo[r0 + reg][col] = c2[i][reg] + b2s[col];
    }
    __syncthreads();

    #pragma unroll
    for (int rr = 0; rr < 4; ++rr) {
        int r = w * 4 + rr;
        float v0 = oo[r][l], v1 = oo[r][l + 64];
        float s = v0 + v1, sq = v0 * v0 + v1 * v1;
        #pragma unroll
        for (int m = 32; m > 0; m >>= 1) {
            s  += __shfl_xor(s, m, 64);
            sq += __shfl_xor(sq, m, 64);
        }
        float mu  = s * (1.0f / 128.0f);
        float var = sq * (1.0f / 128.0f) - mu * mu;
        float rs  = rsqrtf(var + 1e-5f);
        size_t ob = (rowbase + r) * 128;
        outp[ob + l]      = (v0 - mu) * rs * g2s[l]      + bt2s[l]      + xr[r][l];
        outp[ob + l + 64] = (v1 - mu) * rs * g2s[l + 64] + bt2s[l + 64] + xr[r][l + 64];
    }
}

// ---------------------------------------------------------------------------
extern "C" void kernel_launch(void* const* d_in, const int* in_sizes, int n_in,
                              void* d_out, int out_size, void* d_ws, size_t ws_size,
                              hipStream_t stream) {
    const float* x      = (const float*)d_in[0];
    const float* I      = (const float*)d_in[1];
    const float* IX     = (const float*)d_in[2];
    const float* IY     = (const float*)d_in[3];
    const float* IT     = (const float*)d_in[4];
    const float* w_idx  = (const float*)d_in[5];
    const float* b_idx  = (const float*)d_in[6];
    const float* w_proj = (const float*)d_in[7];
    const float* b_proj = (const float*)d_in[8];
    const float* w_mask = (const float*)d_in[9];
    const float* b_mask = (const float*)d_in[10];
    const float* g1     = (const float*)d_in[11];
    const float* beta1  = (const float*)d_in[12];
    const float* w_mlp1 = (const float*)d_in[13];
    const float* b_mlp1 = (const float*)d_in[14];
    const float* w_mlp2 = (const float*)d_in[15];
    const float* b_mlp2 = (const float*)d_in[16];
    const float* g2     = (const float*)d_in[17];
    const float* beta2  = (const float*)d_in[18];
    float* out = (float*)d_out;

    float* ws = (float*)d_ws;
    float*  w_catT  = ws;                          // 49152 f    -> 49152
    ushort* w_projP = (ushort*)(ws + 49152);       // 8192 us    -> 53248
    ushort* w1P     = (ushort*)(ws + 53248);       // 65536 us   -> 86016
    ushort* w2P     = (ushort*)(ws + 86016);       // 65536 us   -> 118784
    float*  maskw   = ws + 118784;                 // 1048576 f  -> 1167360
    uint*   meta    = (uint*)(ws + 1167360);       // 4194304 w  -> 5361664
    uint4*  T1      = (uint4*)(ws + 5361664);      // 2097152 u4 -> 13750272
    ushort* T2      = (ushort*)(ws + 13750272);    // 2097152 us -> 14798848 (59MB)

    kT_pack<<<260, 256, 0, stream>>>(w_idx, w_mask, w_proj, w_mlp1, w_mlp2,
                                     w_catT, w_projP, w1P, w2P);
    k0_coords_mask<<<1024, 256, 0, stream>>>(x, w_catT, b_idx, b_mask,
                                             maskw, meta);
    k1_coeff<<<2048, 256, 0, stream>>>(I, IX, IY, IT, T1, T2);
    k2_rects<<<8192, 256, 0, stream>>>(T1, T2, meta, w_projP, b_proj, maskw,
                                       g1, beta1, out);
    k4_mlp<<<1024, 256, 0, stream>>>(out, w1P, b_mlp1, w2P, b_mlp2, g2, beta2, out);
}

// Round 2
// 96.382 us; speedup vs baseline: 1.1277x; 1.0662x over previous
//
#include <hip/hip_runtime.h>
#include <hip/hip_bf16.h>
#include <hip/hip_fp16.h>
#include <math.h>

#define BB   8
#define DD   1024

typedef short bh8 __attribute__((ext_vector_type(8)));
typedef float f32x4 __attribute__((ext_vector_type(4)));
typedef _Float16 h2f __attribute__((ext_vector_type(2)));

__device__ __forceinline__ ushort f2bf(float f) {
    uint u = __builtin_bit_cast(uint, f);
    u += 0x7fffu + ((u >> 16) & 1u);
    return (ushort)(u >> 16);
}
__device__ __forceinline__ float asf(uint u)  { return __builtin_bit_cast(float, u); }
__device__ __forceinline__ uint  pkh(float a, float b) {
    return __builtin_bit_cast(uint, __builtin_amdgcn_cvt_pkrtz(a, b));
}
__device__ __forceinline__ h2f ash2f(uint u) { return __builtin_bit_cast(h2f, u); }

// v_dot2_f32_f16: a.x*b.x + a.y*b.y + c, f32 accumulate (1 VALU op).
#if __has_builtin(__builtin_amdgcn_fdot2)
__device__ __forceinline__ float fdot2h(h2f a, h2f b, float c) {
    return __builtin_amdgcn_fdot2(a, b, c, false);
}
#else
__device__ __forceinline__ float fdot2h(h2f a, h2f b, float c) {
    return fmaf((float)a.x, (float)b.x, fmaf((float)a.y, (float)b.y, c));
}
#endif

// hardware packed f32->bf16 RTNE (no builtin on gfx950; asm per guide recipe)
__device__ __forceinline__ uint cvtpk_bf16(float a, float b) {
    uint r;
    asm("v_cvt_pk_bf16_f32 %0, %1, %2" : "=v"(r) : "v"(a), "v"(b));
    return r;
}
__device__ __forceinline__ ushort cvt1_bf16(float a) {
    uint r;
    asm("v_cvt_pk_bf16_f32 %0, %1, %2" : "=v"(r) : "v"(a), "v"(a));
    return (ushort)r;
}

// overflow-safe tanh-form gelu via exp2 + rcp
__device__ __forceinline__ float gelu_fast(float x) {
    float x2 = x * x;
#if __has_builtin(__builtin_amdgcn_exp2f)
    float e = __builtin_amdgcn_exp2f(x * fmaf(x2, -0.20588652f, -2.3022082f));
#else
    float e = __expf(-(1.5957691216f * x + 0.14270963f * x * x2));
#endif
    return x * __builtin_amdgcn_rcpf(1.0f + e);
}
__device__ __forceinline__ float sig63(float v) {
    return 63.0f * __builtin_amdgcn_rcpf(1.0f + __expf(-v));
}

// ---------------------------------------------------------------------------
// kT_cat: only the w_catT transpose (k0's dependency). Weight fragment packs
// moved into k01's tail blocks (they're only needed by k2/k4).
// ---------------------------------------------------------------------------
__global__ __launch_bounds__(256) void kT_cat(
    const float* __restrict__ w_idx, const float* __restrict__ w_mask,
    float* __restrict__ w_catT)
{
    int e = blockIdx.x * 256 + threadIdx.x;       // e < 49152
    int k = e / 192, o = e - k * 192;
    const float* src = (o < 64) ? (w_idx + (size_t)o * 256)
                                : (w_mask + (size_t)(o - 64) * 256);
    w_catT[e] = src[k];
}

// ---------------------------------------------------------------------------
// k01: fat kernel.
//   blocks [0,1024)    : k0 coords+mask GEMM + meta epilogue (VALU-heavy)
//   blocks [1024,3072) : k1 texture coefficients (memory-heavy)
//   blocks [3072,3140) : weight fragment packs for k2/k4
// k0/k1 are independent; overlapping them fills both pipes.
// ---------------------------------------------------------------------------
__global__ __launch_bounds__(256) void k01(
    const float* __restrict__ x, const float* __restrict__ w_catT,
    const float* __restrict__ b_idx, const float* __restrict__ b_mask,
    float* __restrict__ maskw, uint* __restrict__ meta,
    const float* __restrict__ I, const float* __restrict__ IX,
    const float* __restrict__ IY, const float* __restrict__ IT,
    uint4* __restrict__ T1, ushort* __restrict__ T2,
    const float* __restrict__ w_proj, const float* __restrict__ w1,
    const float* __restrict__ w2,
    ushort* __restrict__ w_projP, ushort* __restrict__ w1P,
    ushort* __restrict__ w2P)
{
    __shared__ __align__(16) char smem[24960];
    int t = threadIdx.x;
    int bid = blockIdx.x;

    if (bid < 1024) {
        // ---------------- k0: coords + mask ----------------
        float (*xs)[256]   = (float (*)[256])(smem);
        float (*sOut)[192] = (float (*)[192])(smem + 8192);
        size_t rowbase = (size_t)bid * 8;

        for (int i = t; i < 2048; i += 256) xs[i >> 8][i & 255] = x[rowbase * 256 + i];
        __syncthreads();

        if (t < 192) {
            float acc[8] = {0.f, 0.f, 0.f, 0.f, 0.f, 0.f, 0.f, 0.f};
            #pragma unroll 4
            for (int k = 0; k < 256; ++k) {
                float wv = w_catT[k * 192 + t];
                #pragma unroll
                for (int r = 0; r < 8; ++r) acc[r] += xs[r][k] * wv;
            }
            #pragma unroll
            for (int r = 0; r < 8; ++r) sOut[r][t] = acc[r];
        }
        __syncthreads();

        if (t < 128) {
            int row = t >> 4, u = t & 15, br = u >> 3, nr = u & 7;
            int c0 = br * 32 + nr * 4;
            float x1 = sig63(sOut[row][c0 + 0] + b_idx[c0 + 0]);
            float y1 = sig63(sOut[row][c0 + 1] + b_idx[c0 + 1]);
            float x2 = sig63(sOut[row][c0 + 2] + b_idx[c0 + 2]);
            float y2 = sig63(sOut[row][c0 + 3] + b_idx[c0 + 3]);
            int X1 = (int)ceilf(x1); X1 = X1 < 1 ? 1 : (X1 > 63 ? 63 : X1);
            int X2 = (int)ceilf(x2); X2 = X2 < 1 ? 1 : (X2 > 63 ? 63 : X2);
            int Y1 = (int)ceilf(y1); Y1 = Y1 < 1 ? 1 : (Y1 > 63 ? 63 : Y1);
            int Y2 = (int)ceilf(y2); Y2 = Y2 < 1 ? 1 : (Y2 > 63 ? 63 : Y2);
            float dxa = (float)X1 - x1, dxb = (float)X2 - x2;
            float dya = (float)Y1 - y1, dyb = (float)Y2 - y2;
            int   Xc[4] = {X2, X1, X2, X1};
            int   Yc[4] = {Y2, Y2, Y1, Y1};
            float sg[4] = {1.f, -1.f, -1.f, 1.f};
            float dxc[4] = {dxb, dxa, dxb, dxa};
            float dyc[4] = {dyb, dyb, dya, dya};
            uint* mr = meta + (((rowbase + row) * 16) + (size_t)u) * 32;
            #pragma unroll
            for (int c = 0; c < 4; ++c) {
                uint pt = (uint)(Xc[c] * 64 + Yc[c]);
                float s = sg[c], dx = dxc[c], dy = dyc[c];
                float dx2 = dx * dx, dy2 = dy * dy;
                uint4 wa, wb;
                wa.x = pt * 1024u;
                wa.y = pt * 128u;
                wa.z = pkh(s, s * dy);
                wa.w = pkh(s * dy2, s * dx);
                wb.x = pkh(s * dx2, s * dx * dy);
                wb.y = pkh(s * dx * dy2, s * dx2 * dy);
                wb.z = __builtin_bit_cast(uint, s * dx2 * dy2);
                wb.w = 0u;
                *(uint4*)(mr + c * 8 + 0) = wa;
                *(uint4*)(mr + c * 8 + 4) = wb;
            }
        } else {
            int tt = t - 128;
            int row = tt >> 4, br = (tt >> 3) & 1, g = tt & 7;
            float lg[8];
            float mx = -1e30f;
            #pragma unroll
            for (int nr = 0; nr < 8; ++nr) {
                int idx = br * 64 + nr * 8 + g;
                lg[nr] = sOut[row][64 + idx] + b_mask[idx];
                mx = fmaxf(mx, lg[nr]);
            }
            float s = 0.f;
            #pragma unroll
            for (int nr = 0; nr < 8; ++nr) { lg[nr] = __expf(lg[nr] - mx); s += lg[nr]; }
            float inv = __builtin_amdgcn_rcpf(s);
            #pragma unroll
            for (int nr = 0; nr < 8; ++nr)
                maskw[(rowbase + row) * 128 + br * 64 + nr * 8 + g] = lg[nr] * inv;
        }
    } else if (bid < 3072) {
        // ---------------- k1: 9-coeff texture ----------------
        float (*tI)[65]  = (float (*)[65])(smem);
        float (*tIp)[65] = (float (*)[65])(smem + 4160);
        float (*tX)[65]  = (float (*)[65])(smem + 8320);
        float (*tY)[65]  = (float (*)[65])(smem + 12480);
        float (*tYp)[65] = (float (*)[65])(smem + 16640);
        float (*tT)[65]  = (float (*)[65])(smem + 20800);
        int kb = bid - 1024;                  // b(8) x h(64) x chunk(4)
        int chunk = kb & 3, h = (kb >> 2) & 63, b = kb >> 8;
        int hp = h > 0 ? h - 1 : 0;
        int cb = chunk * 16;
        size_t inb  = (size_t)b * 262144 + (size_t)h  * 64;
        size_t inbp = (size_t)b * 262144 + (size_t)hp * 64;

        #pragma unroll
        for (int i = 0; i < 4; ++i) {
            int idx = i * 256 + t; int c = idx >> 6, w = idx & 63;
            size_t o = (size_t)(cb + c) * 4096 + w;
            tI[c][w]  = I[inb + o];
            tIp[c][w] = I[inbp + o];
            tX[c][w]  = IX[inb + o];
            tY[c][w]  = IY[inb + o];
            tYp[c][w] = IY[inbp + o];
            tT[c][w]  = IT[inb + o];
        }
        __syncthreads();

        #pragma unroll
        for (int i = 0; i < 4; ++i) {
            int idx = i * 256 + t; int w = idx >> 4, c = idx & 15;
            int wm = w > 0 ? w - 1 : 0;
            float I00 = tI[c][w], I0m = tI[c][wm];
            float Im0 = tIp[c][w], Imm = tIp[c][wm];
            float E1  = tX[c][w]  - 0.5f * I00;
            float E1m = tX[c][wm] - 0.5f * I0m;
            float E2  = tY[c][w]  - 0.5f * I00;
            float E2m = tYp[c][w] - 0.5f * Im0;
            float v0 = tT[c][w];
            float v1 = -E1;
            float v2 = 0.5f * (E1 - E1m);
            float v3 = -E2;
            float v4 = 0.5f * (E2 - E2m);
            float v5 = I00;
            float v6 = 0.5f * (I0m - I00);
            float v7 = 0.5f * (Im0 - I00);
            float v8 = 0.25f * ((Imm - I0m) - (Im0 - I00));
            size_t pt = (((size_t)b * 4096) + (size_t)h * 64 + w) * 64 + (cb + c);
            uint4 o4;
            o4.x = pkh(v0, v1);
            o4.y = pkh(v2, v3);
            o4.z = pkh(v4, v5);
            o4.w = pkh(v6, v7);
            T1[pt] = o4;
            T2[pt] = (ushort)(pkh(v8, 0.f) & 0xffffu);
        }
    } else {
        // ---------------- weight fragment packs (for k2/k4) ----------------
        int e = (bid - 3072 + 192) * 256 + t;     // e in [49152, 66560)
        if (e < 50176) {             // w_proj (128,64): B[k=c][n=dch]
            int g = e - 49152; int nt = g >> 7, ks = (g >> 6) & 1, l = g & 63;
            int n = nt * 16 + (l & 15), k0 = ks * 32 + (l >> 4) * 8;
            ushort* dst = w_projP + (size_t)g * 8;
            #pragma unroll
            for (int j = 0; j < 8; ++j) dst[j] = f2bf(w_proj[n * 64 + k0 + j]);
        } else if (e < 58368) {      // w_mlp1 (512,128): B[k][n]
            int g = e - 50176; int nt = g >> 8, ks = (g >> 6) & 3, l = g & 63;
            int n = nt * 16 + (l & 15), k0 = ks * 32 + (l >> 4) * 8;
            ushort* dst = w1P + (size_t)g * 8;
            #pragma unroll
            for (int j = 0; j < 8; ++j) dst[j] = f2bf(w1[n * 128 + k0 + j]);
        } else if (e < 66560) {      // w_mlp2 (128,512): B[k][n]
            int g = e - 58368; int nt = g >> 10, ks = (g >> 6) & 15, l = g & 63;
            int n = nt * 16 + (l & 15), k0 = ks * 32 + (l >> 4) * 8;
            ushort* dst = w2P + (size_t)g * 8;
            #pragma unroll
            for (int j = 0; j < 8; ++j) dst[j] = f2bf(w2[n * 512 + k0 + j]);
        }
    }
}

// ---------------------------------------------------------------------------
// k2: fused sampling + rects GEMM + gelu + mask-sum + LN1.
// Software-pipelined: group rr+1's 8 gather loads are issued BEFORE group
// rr's fdot chain, hiding the ~200-300cy L2-hit latency under compute.
// ---------------------------------------------------------------------------
__global__ __launch_bounds__(256) void k2_rects(
    const uint4* __restrict__ T1, const ushort* __restrict__ T2,
    const uint* __restrict__ meta,
    const ushort* __restrict__ w_projP, const float* __restrict__ b_proj,
    const float* __restrict__ maskw, const float* __restrict__ g1,
    const float* __restrict__ beta1, float* __restrict__ mid)
{
    __shared__ __align__(16) uint meta_lds[16][32];
    __shared__ __align__(16) float S_lds[16][68];
    __shared__ float mrow[128];
    __shared__ float outr[2][128];
    int bid = blockIdx.x;
    int b = bid & 7, d = bid >> 3;
    int t = threadIdx.x, w = t >> 6, l = t & 63;
    size_t tile = (size_t)b * DD + d;
    if (t < 128) {
        uint4 mv = *(const uint4*)(meta + tile * 512 + (size_t)t * 4);
        *(uint4*)(&meta_lds[0][0] + t * 4) = mv;
    }
    if (t >= 128) mrow[t - 128] = maskw[tile * 128 + (t - 128)];

    bh8 bf[2][2];
    #pragma unroll
    for (int ni = 0; ni < 2; ++ni) {
        int nt = w * 2 + ni;
        #pragma unroll
        for (int ks = 0; ks < 2; ++ks)
            bf[ni][ks] = *(const bh8*)(w_projP + ((size_t)(nt * 2 + ks) * 64 + l) * 8);
    }
    __syncthreads();
    const char* t1b = ((const char*)T1) + ((size_t)b << 22) + (size_t)(l * 16);
    const char* t2b = ((const char*)T2) + ((size_t)b << 19) + (size_t)(l * 2);

    uint4 q[4]; ushort e8[4];
    {
        int m0 = w * 4;
        #pragma unroll
        for (int c = 0; c < 4; ++c) {
            q[c]  = *(const uint4*)(t1b + meta_lds[m0][c * 8 + 0]);
            e8[c] = *(const ushort*)(t2b + meta_lds[m0][c * 8 + 1]);
        }
    }
    #pragma unroll
    for (int rr = 0; rr < 4; ++rr) {
        int m = w * 4 + rr;
        uint4 qc[4]; ushort ec[4];
        #pragma unroll
        for (int c = 0; c < 4; ++c) { qc[c] = q[c]; ec[c] = e8[c]; }
        if (rr < 3) {
            int mn = m + 1;
            #pragma unroll
            for (int c = 0; c < 4; ++c) {
                q[c]  = *(const uint4*)(t1b + meta_lds[mn][c * 8 + 0]);
                e8[c] = *(const ushort*)(t2b + meta_lds[mn][c * 8 + 1]);
            }
        }
        float acc0 = 0.f, acc1 = 0.f;
        #pragma unroll
        for (int c = 0; c < 4; ++c) {
            uint cz = meta_lds[m][c * 8 + 2], cw = meta_lds[m][c * 8 + 3];
            uint bx = meta_lds[m][c * 8 + 4], by = meta_lds[m][c * 8 + 5];
            float bz = asf(meta_lds[m][c * 8 + 6]);
            float ev = __half2float(__builtin_bit_cast(__half, ec[c]));
            float cv = bz * ev;
            cv = fdot2h(ash2f(by), ash2f(qc[c].w), cv);
            cv = fdot2h(ash2f(bx), ash2f(qc[c].z), cv);
            cv = fdot2h(ash2f(cw), ash2f(qc[c].y), cv);
            cv = fdot2h(ash2f(cz), ash2f(qc[c].x), cv);
            if (c & 1) acc1 += cv; else acc0 += cv;
        }
        S_lds[m][l] = acc0 + acc1;
    }
    __syncthreads();

    // MFMA: A from S_lds (bf16 via v_cvt_pk_bf16_f32), B = w_proj fragments
    int am = l & 15, q2 = l >> 4;
    bh8 a0, a1;
    {
        float4 va = *(const float4*)&S_lds[am][q2 * 8];
        float4 vb = *(const float4*)&S_lds[am][q2 * 8 + 4];
        uint4 ua;
        ua.x = cvtpk_bf16(va.x, va.y);
        ua.y = cvtpk_bf16(va.z, va.w);
        ua.z = cvtpk_bf16(vb.x, vb.y);
        ua.w = cvtpk_bf16(vb.z, vb.w);
        a0 = __builtin_bit_cast(bh8, ua);
        float4 vc = *(const float4*)&S_lds[am][32 + q2 * 8];
        float4 vd = *(const float4*)&S_lds[am][32 + q2 * 8 + 4];
        uint4 ub;
        ub.x = cvtpk_bf16(vc.x, vc.y);
        ub.y = cvtpk_bf16(vc.z, vc.w);
        ub.z = cvtpk_bf16(vd.x, vd.y);
        ub.w = cvtpk_bf16(vd.z, vd.w);
        a1 = __builtin_bit_cast(bh8, ub);
    }
    f32x4 cc[2];
    cc[0] = (f32x4){0.f, 0.f, 0.f, 0.f};
    cc[1] = (f32x4){0.f, 0.f, 0.f, 0.f};
    cc[0] = __builtin_amdgcn_mfma_f32_16x16x32_bf16(a0, bf[0][0], cc[0], 0, 0, 0);
    cc[0] = __builtin_amdgcn_mfma_f32_16x16x32_bf16(a1, bf[0][1], cc[0], 0, 0, 0);
    cc[1] = __builtin_amdgcn_mfma_f32_16x16x32_bf16(a0, bf[1][0], cc[1], 0, 0, 0);
    cc[1] = __builtin_amdgcn_mfma_f32_16x16x32_bf16(a1, bf[1][1], cc[1], 0, 0, 0);

    int cl = l & 15;
    #pragma unroll
    for (int ni = 0; ni < 2; ++ni) {
        int nt = w * 2 + ni;
        int col = nt * 16 + cl;
        float bpv = b_proj[col];
        float p = 0.f;
        #pragma unroll
        for (int reg = 0; reg < 4; ++reg) {
            int r = q2 * 4 + reg;                      // row = br*8+nr
            float v = cc[ni][reg] + bpv;
            p += gelu_fast(v) * mrow[(r >> 3) * 64 + (r & 7) * 8 + nt];
        }
        p += __shfl_xor(p, 16, 64);
        if (q2 == 0) outr[0][col] = p;
        else if (q2 == 2) outr[1][col] = p;
    }
    __syncthreads();

    if (w < 2) {
        float v0 = outr[w][l], v1 = outr[w][l + 64];
        float s = v0 + v1, sq = v0 * v0 + v1 * v1;
        #pragma unroll
        for (int mm = 32; mm > 0; mm >>= 1) {
            s  += __shfl_xor(s, mm, 64);
            sq += __shfl_xor(sq, mm, 64);
        }
        float mu  = s * (1.0f / 128.0f);
        float var = sq * (1.0f / 128.0f) - mu * mu;
        float rs  = rsqrtf(var + 1e-5f);
        size_t ob = (tile * 2 + w) * 128;
        mid[ob + l]      = (v0 - mu) * rs * g1[l]      + beta1[l];
        mid[ob + l + 64] = (v1 - mu) * rs * g1[l + 64] + beta1[l + 64];
    }
}

// ---------------------------------------------------------------------------
// k4: MLP 128->512(gelu)->128 via MFMA, 16 rows/block, + LN2 + residual.
// ---------------------------------------------------------------------------
__global__ __launch_bounds__(256) void k4_mlp(
    const float* __restrict__ mid, const ushort* __restrict__ w1P,
    const float* __restrict__ b1, const ushort* __restrict__ w2P,
    const float* __restrict__ b2, const float* __restrict__ g2,
    const float* __restrict__ beta2, float* __restrict__ outp)
{
    __shared__ float xr[16][132];
    __shared__ __align__(16) ushort Af[4][64][8];
    __shared__ __align__(16) ushort H[16][520];
    __shared__ float oo[16][128];
    __shared__ float b1s[512];
    __shared__ float b2s[128], g2s[128], bt2s[128];
    int t = threadIdx.x, w = t >> 6, l = t & 63;
    int bid = blockIdx.x;
    int mt = (bid & 7) * 128 + (bid >> 3);   // XCD-local by batch
    size_t rowbase = (size_t)mt * 16;

    for (int i = t; i < 2048; i += 256) xr[i >> 7][i & 127] = mid[rowbase * 128 + i];
    for (int i = t; i < 512; i += 256) b1s[i] = b1[i];
    if (t < 128) { b2s[t] = b2[t]; g2s[t] = g2[t]; bt2s[t] = beta2[t]; }
    __syncthreads();

    {
        int ks = t >> 6, m = l & 15, c0 = ks * 32 + (l >> 4) * 8;
        uint* dst = (uint*)&Af[ks][l][0];
        #pragma unroll
        for (int j = 0; j < 4; ++j)
            dst[j] = cvtpk_bf16(xr[m][c0 + 2 * j], xr[m][c0 + 2 * j + 1]);
    }
    __syncthreads();

    f32x4 c1[8];
    #pragma unroll
    for (int i = 0; i < 8; ++i) c1[i] = (f32x4){0.f, 0.f, 0.f, 0.f};
    bh8 a[4];
    #pragma unroll
    for (int ks = 0; ks < 4; ++ks) a[ks] = *(const bh8*)&Af[ks][l][0];
    #pragma unroll
    for (int ni = 0; ni < 8; ++ni) {
        int nt = w * 8 + ni;
        #pragma unroll
        for (int ks = 0; ks < 4; ++ks) {
            bh8 bfr = *(const bh8*)(w1P + ((size_t)(nt * 4 + ks) * 64 + l) * 8);
            c1[ni] = __builtin_amdgcn_mfma_f32_16x16x32_bf16(a[ks], bfr, c1[ni], 0, 0, 0);
        }
    }
    #pragma unroll
    for (int ni = 0; ni < 8; ++ni) {
        int nt = w * 8 + ni;
        int col = nt * 16 + (l & 15);
        int r0 = (l >> 4) * 4;
        #pragma unroll
        for (int reg = 0; reg < 4; ++reg)
            H[r0 + reg][col] = cvt1_bf16(gelu_fast(c1[ni][reg] + b1s[col]));
    }
    __syncthreads();

    f32x4 c2[2];
    c2[0] = (f32x4){0.f, 0.f, 0.f, 0.f};
    c2[1] = (f32x4){0.f, 0.f, 0.f, 0.f};
    const char* hb = (const char*)&H[0][0];
    #pragma unroll
    for (int ks2 = 0; ks2 < 16; ++ks2) {
        bh8 af = *(const bh8*)(hb + (l & 15) * 1040 + ks2 * 64 + (l >> 4) * 16);
        #pragma unroll
        for (int i = 0; i < 2; ++i) {
            int nt2 = w * 2 + i;
            bh8 bfr = *(const bh8*)(w2P + ((size_t)(nt2 * 16 + ks2) * 64 + l) * 8);
            c2[i] = __builtin_amdgcn_mfma_f32_16x16x32_bf16(af, bfr, c2[i], 0, 0, 0);
        }
    }
    #pragma unroll
    for (int i = 0; i < 2; ++i) {
        int col = (w * 2 + i) * 16 + (l & 15);
        int r0 = (l >> 4) * 4;
        #pragma unroll
        for (int reg = 0; reg < 4; ++reg) oo[r0 + reg][col] = c2[i][reg] + b2s[col];
    }
    __syncthreads();

    #pragma unroll
    for (int rr = 0; rr < 4; ++rr) {
        int r = w * 4 + rr;
        float v0 = oo[r][l], v1 = oo[r][l + 64];
        float s = v0 + v1, sq = v0 * v0 + v1 * v1;
        #pragma unroll
        for (int m = 32; m > 0; m >>= 1) {
            s  += __shfl_xor(s, m, 64);
            sq += __shfl_xor(sq, m, 64);
        }
        float mu  = s * (1.0f / 128.0f);
        float var = sq * (1.0f / 128.0f) - mu * mu;
        float rs  = rsqrtf(var + 1e-5f);
        size_t ob = (rowbase + r) * 128;
        outp[ob + l]      = (v0 - mu) * rs * g2s[l]      + bt2s[l]      + xr[r][l];
        outp[ob + l + 64] = (v1 - mu) * rs * g2s[l + 64] + bt2s[l + 64] + xr[r][l + 64];
    }
}

// ---------------------------------------------------------------------------
extern "C" void kernel_launch(void* const* d_in, const int* in_sizes, int n_in,
                              void* d_out, int out_size, void* d_ws, size_t ws_size,
                              hipStream_t stream) {
    const float* x      = (const float*)d_in[0];
    const float* I      = (const float*)d_in[1];
    const float* IX     = (const float*)d_in[2];
    const float* IY     = (const float*)d_in[3];
    const float* IT     = (const float*)d_in[4];
    const float* w_idx  = (const float*)d_in[5];
    const float* b_idx  = (const float*)d_in[6];
    const float* w_proj = (const float*)d_in[7];
    const float* b_proj = (const float*)d_in[8];
    const float* w_mask = (const float*)d_in[9];
    const float* b_mask = (const float*)d_in[10];
    const float* g1     = (const float*)d_in[11];
    const float* beta1  = (const float*)d_in[12];
    const float* w_mlp1 = (const float*)d_in[13];
    const float* b_mlp1 = (const float*)d_in[14];
    const float* w_mlp2 = (const float*)d_in[15];
    const float* b_mlp2 = (const float*)d_in[16];
    const float* g2     = (const float*)d_in[17];
    const float* beta2  = (const float*)d_in[18];
    float* out = (float*)d_out;

    float* ws = (float*)d_ws;
    float*  w_catT  = ws;                          // 49152 f    -> 49152
    ushort* w_projP = (ushort*)(ws + 49152);       // 8192 us    -> 53248
    ushort* w1P     = (ushort*)(ws + 53248);       // 65536 us   -> 86016
    ushort* w2P     = (ushort*)(ws + 86016);       // 65536 us   -> 118784
    float*  maskw   = ws + 118784;                 // 1048576 f  -> 1167360
    uint*   meta    = (uint*)(ws + 1167360);       // 4194304 w  -> 5361664
    uint4*  T1      = (uint4*)(ws + 5361664);      // 2097152 u4 -> 13750272
    ushort* T2      = (ushort*)(ws + 13750272);    // 2097152 us -> 14798848 (59MB)

    kT_cat<<<192, 256, 0, stream>>>(w_idx, w_mask, w_catT);
    k01<<<3140, 256, 0, stream>>>(x, w_catT, b_idx, b_mask, maskw, meta,
                                  I, IX, IY, IT, T1, T2,
                                  w_proj, w_mlp1, w_mlp2,
                                  w_projP, w1P, w2P);
    k2_rects<<<8192, 256, 0, stream>>>(T1, T2, meta, w_projP, b_proj, maskw,
                                       g1, beta1, out);
    k4_mlp<<<1024, 256, 0, stream>>>(out, w1P, b_mlp1, w2P, b_mlp2, g2, beta2, out);
}